// Round 3
// baseline (503.460 us; speedup 1.0000x reference)
//
#include <hip/hip_runtime.h>
#include <hip/hip_bf16.h>
#include <cstdint>
#include <cstddef>

#define SEQ 512
#define BATCH 256
#define IN_DIM 300
#define HID 256

typedef __attribute__((ext_vector_type(8))) short bf16x8;
typedef __attribute__((ext_vector_type(4))) float f32x4;
typedef __attribute__((ext_vector_type(4))) unsigned int u32x4;

__device__ __forceinline__ unsigned short f2bf(float f) {
  union { float f; unsigned int u; } v; v.f = f;
  unsigned int u = v.u;
  return (unsigned short)((u + 0x7fffu + ((u >> 16) & 1u)) >> 16);  // RNE
}
__device__ __forceinline__ unsigned short f2bf_fast(float f) {
  union { float f; unsigned int u; } v; v.f = f;
  return (unsigned short)((v.u + 0x8000u) >> 16);  // round-half-up, err <= 2^-9 rel
}
__device__ __forceinline__ float bitsf(unsigned int u) {
  union { unsigned int u; float f; } v; v.u = u; return v.f;
}
// HW cvt_pk RNE pack of two f32 -> one dword (low = lo).
__device__ __forceinline__ unsigned int cvtpk(float lo, float hi) {
  union { __hip_bfloat162 h; unsigned int u; } c;
  c.h = __float22bfloat162_rn(make_float2(lo, hi));
  return c.u;
}
__device__ __forceinline__ bf16x8 cvt8(float a0,float a1,float a2,float a3,
                                       float a4,float a5,float a6,float a7) {
  union { __hip_bfloat162 h2[4]; bf16x8 v; } c;
  c.h2[0] = __float22bfloat162_rn(make_float2(a0, a1));
  c.h2[1] = __float22bfloat162_rn(make_float2(a2, a3));
  c.h2[2] = __float22bfloat162_rn(make_float2(a4, a5));
  c.h2[3] = __float22bfloat162_rn(make_float2(a6, a7));
  return c.v;
}
// Raw workgroup barrier with LDS-only drain: does NOT force vmcnt(0), so
// global-load prefetches stay in flight across the barrier (T4 pattern).
// Always executed in block-uniform control flow.
__device__ __forceinline__ void barrier_lgkm() {
  asm volatile("s_waitcnt lgkmcnt(0)" ::: "memory");
  __builtin_amdgcn_s_barrier();
  asm volatile("" ::: "memory");
}

struct F8 { float v[8]; };
// guarded 8-float row load (zero-pad past IN_DIM); fully unrolled -> registers
__device__ __forceinline__ F8 load_x8(const float* __restrict__ xrow, int k0, int ac) {
  F8 r;
  if (k0 + ac + 8 <= IN_DIM) {
    float2 p0 = *(const float2*)(xrow + k0 + ac + 0);
    float2 p1 = *(const float2*)(xrow + k0 + ac + 2);
    float2 p2 = *(const float2*)(xrow + k0 + ac + 4);
    float2 p3 = *(const float2*)(xrow + k0 + ac + 6);
    r.v[0]=p0.x; r.v[1]=p0.y; r.v[2]=p1.x; r.v[3]=p1.y;
    r.v[4]=p2.x; r.v[5]=p2.y; r.v[6]=p3.x; r.v[7]=p3.y;
  } else {
    #pragma unroll
    for (int j = 0; j < 8; ++j)
      r.v[j] = (k0 + ac + j < IN_DIM) ? xrow[k0 + ac + j] : 0.f;
  }
  return r;
}

// ---------------- kernel 0: W_ih fp32 -> bf16, FRAGMENT-MAJOR layout.
// Short index: (((n16*10 + kc)*4 + quad)*16 + l15)*8 + j
//   value = W_ih[n16*16 + l15][kc*32 + quad*8 + j]  (0 if k >= 300)
// gemm_xp lane (wave,l15,quad) then loads wf[nt][kc] as 16B at consecutive
// l15 -> fully coalesced 1 KB per wave-instruction (was 640-B lane stride).
__global__ __launch_bounds__(256) void conv_wih(const float* __restrict__ w,
                                                unsigned short* __restrict__ w_bf) {
  int idx = blockIdx.x * 256 + threadIdx.x;    // 0..81919
  int j    = idx & 7;
  int l15  = (idx >> 3) & 15;
  int quad = (idx >> 7) & 3;
  int t    = idx >> 9;                         // n16*10 + kc
  int n16  = t / 10;
  int kc   = t - n16 * 10;
  int n = n16 * 16 + l15;
  int k = kc * 32 + quad * 8 + j;
  float v = (k < IN_DIM) ? w[n * IN_DIM + k] : 0.f;
  w_bf[idx] = f2bf(v);
}

// ---------------- kernel 1: xp2 (permuted, bf16) = 2*(x@W_ih^T + b_ih + b_hh)
// 1024 blocks x 512 thr, 128-row M-tile. W fragments in registers for the
// whole kernel (coalesced fragment-major loads). Double-buffered A-tile LDS:
// ONE barrier per kc (was 2). x-prefetch depth 2: loads for kc+2 issued at
// kc, ~2 full kc bodies (> HBM latency) to land. afr reads hoisted before
// the LDS writes so MFMAs start as soon as lgkmcnt drains the reads.
// Output layout contract with rnn_scan unchanged:
//   value (t,b,n): g=b>>2, rr=b&3, tid_s=(n>>5)*64+((rr>>1)*2+((n>>4)&1))*16+(n&15)
//   dword = (t*64+g)*512 + tid_s; low short = rr even.
__global__ __launch_bounds__(512, 2) void gemm_xp(const float* __restrict__ x,
    const unsigned short* __restrict__ w_bf, const float* __restrict__ b_ih,
    const float* __restrict__ b_hh, unsigned int* __restrict__ xp2)
{
  __shared__ unsigned int a_lds[2][128][20];   // packed bf16 pairs, row stride 80 B
  const int tid  = threadIdx.x;
  const int wave = tid >> 6;
  const int lane = tid & 63;
  const int l15  = lane & 15;
  const int quad = lane >> 4;
  const long m0  = (long)blockIdx.x * 128;

  // B fragments, fragment-major coalesced: n16 = wave*2+nt
  bf16x8 wf[2][10];
  #pragma unroll
  for (int nt = 0; nt < 2; ++nt) {
    const unsigned short* wp =
        w_bf + ((size_t)((wave*2 + nt)*10)*4 + quad)*16*8 + (size_t)l15*8;
    #pragma unroll
    for (int kc = 0; kc < 10; ++kc)
      wf[nt][kc] = *(const bf16x8*)(wp + (size_t)kc*4*16*8);
  }

  f32x4 acc[8][2];
  #pragma unroll
  for (int mt = 0; mt < 8; ++mt) {
    acc[mt][0] = (f32x4){0.f, 0.f, 0.f, 0.f};
    acc[mt][1] = (f32x4){0.f, 0.f, 0.f, 0.f};
  }

  const int ar = tid >> 2;            // A row 0..127
  const int ac = (tid & 3) * 8;       // A col base 0/8/16/24
  const float* xrow = x + (size_t)(m0 + ar) * IN_DIM;

  F8 av[2];
  av[0] = load_x8(xrow, 0, ac);       // kc=0
  av[1] = load_x8(xrow, 32, ac);      // kc=1
  {
    u32x4 pk;
    pk.x = cvtpk(av[0].v[0], av[0].v[1]);
    pk.y = cvtpk(av[0].v[2], av[0].v[3]);
    pk.z = cvtpk(av[0].v[4], av[0].v[5]);
    pk.w = cvtpk(av[0].v[6], av[0].v[7]);
    *(u32x4*)&a_lds[0][ar][(tid & 3) * 4] = pk;
  }
  barrier_lgkm();

  #pragma unroll
  for (int kc = 0; kc < 10; ++kc) {
    const int cur = kc & 1;
    // hoist all A-frag reads (issue first; MFMAs below drain them fine-grained)
    bf16x8 afr[8];
    #pragma unroll
    for (int mt = 0; mt < 8; ++mt)
      afr[mt] = *(const bf16x8*)&a_lds[cur][mt*16 + l15][quad*4];
    // stage kc+1 into the other buffer (its readers finished last barrier)
    if (kc < 9) {
      const int s = (kc + 1) & 1;
      u32x4 pk;
      pk.x = cvtpk(av[s].v[0], av[s].v[1]);
      pk.y = cvtpk(av[s].v[2], av[s].v[3]);
      pk.z = cvtpk(av[s].v[4], av[s].v[5]);
      pk.w = cvtpk(av[s].v[6], av[s].v[7]);
      *(u32x4*)&a_lds[s][ar][(tid & 3) * 4] = pk;
    }
    // issue loads for kc+2 (slot kc&1 is free: its data was staged last iter)
    if (kc < 8)
      av[kc & 1] = load_x8(xrow, (kc + 2) * 32, ac);
    #pragma unroll
    for (int mt = 0; mt < 8; ++mt) {
      acc[mt][0] = __builtin_amdgcn_mfma_f32_16x16x32_bf16(afr[mt], wf[0][kc], acc[mt][0], 0, 0, 0);
      acc[mt][1] = __builtin_amdgcn_mfma_f32_16x16x32_bf16(afr[mt], wf[1][kc], acc[mt][1], 0, 0, 0);
    }
    barrier_lgkm();   // writes to buf[s] visible; readers of buf[cur] done
  }

  // epilogue: scatter to scan-permuted layout (bit-identical formula/rounding)
  const int t  = (int)(blockIdx.x >> 1);
  const int b4 = ((int)blockIdx.x & 1) * 32;
  #pragma unroll
  for (int nt = 0; nt < 2; ++nt) {
    const int n = wave*32 + nt*16 + l15;
    const float kb = 2.0f * (b_ih[n] + b_hh[n]);
    const int tid_lo = wave*64 + nt*16 + l15;
    #pragma unroll
    for (int mt = 0; mt < 8; ++mt) {
      const int g = b4 + mt*4 + quad;
      const size_t base = ((size_t)t*64 + g) * 512;
      float y0 = fmaf(2.0f, acc[mt][nt][0], kb);
      float y1 = fmaf(2.0f, acc[mt][nt][1], kb);
      float y2 = fmaf(2.0f, acc[mt][nt][2], kb);
      float y3 = fmaf(2.0f, acc[mt][nt][3], kb);
      xp2[base + tid_lo]      = cvtpk(y0, y1);
      xp2[base + tid_lo + 32] = cvtpk(y2, y3);
    }
  }
}

// ---------------- kernel 2: sequential scan. 64 blocks x 512 thr (8 waves).
// This round: __launch_bounds__(512,2) raises the VGPR cap to 256 (grid=64
// means >1 block/CU was never reachable; the old default pushed wf/xq/acc
// state into AGPRs -> per-step v_accvgpr traffic on the serial chain).
// Quad accumulators: MFMA chain depth 4 -> 2 (shorter serial tail; f32
// reassociation noise << bf16 rounding). s_setprio(1) around MFMA cluster.
__global__ __launch_bounds__(512, 2) void rnn_scan(const float* __restrict__ W_hh,
    const unsigned int* __restrict__ xp2, float* __restrict__ hT)
{
  __shared__ alignas(16) unsigned short hbuf[2][4 * 272];
  const int tid  = threadIdx.x;
  const int wave = tid >> 6;
  const int lane = tid & 63;
  const int l15  = lane & 15;
  const int quad = lane >> 4;
  const int g = blockIdx.x;
  const int c0 = wave * 32;

  // B fragments: B[k=quad*8+j][n=l15] = W_hh[n][k]
  bf16x8 wf[2][8];
  #pragma unroll
  for (int nt = 0; nt < 2; ++nt) {
    const int n = c0 + nt*16 + l15;
    #pragma unroll
    for (int kc = 0; kc < 8; ++kc) {
      const float* src = W_hh + n*HID + kc*32 + quad*8;
      float4 p0 = *(const float4*)src;
      float4 p1 = *(const float4*)(src + 4);
      wf[nt][kc] = cvt8(p0.x,p0.y,p0.z,p0.w,p1.x,p1.y,p1.z,p1.w);
    }
  }

  const int rb    = (quad >> 1) * 2;                 // batch pair base: rb, rb+1
  const int col_e = c0 + (quad & 1) * 16 + l15;      // epilogue hidden col
  const int abase = (l15 & 3) * 272 + quad * 8;      // A-frag read base

  for (int i = tid; i < 4 * 272; i += 512) hbuf[0][i] = 0;  // h0 = 0

  const unsigned int* xbase = xp2 + (size_t)g * 512 + tid;  // t stride 64*512 dwords

  __syncthreads();

  unsigned int xq[16], xqn[16];
  #pragma unroll
  for (int j = 0; j < 16; ++j)                       // preload tc=0
    xq[j] = xbase[(size_t)j * 32768];

  for (int tc = 0; tc < SEQ / 16; ++tc) {
    if (tc < SEQ/16 - 1) {                           // issue tc+1 burst early
      const unsigned int* pn = xbase + (size_t)(tc + 1) * 16 * 32768;
      #pragma unroll
      for (int j = 0; j < 16; ++j)
        xqn[j] = pn[(size_t)j * 32768];
    }
    #pragma unroll
    for (int j = 0; j < 16; ++j) {
      const int cur = j & 1;                         // t parity == j parity
      bf16x8 afr[8];
      #pragma unroll
      for (int kc = 0; kc < 8; ++kc)
        afr[kc] = *(const bf16x8*)&hbuf[cur][abase + kc*32];
      // quad accumulators per nt: chain depth 2 (was 4)
      f32x4 a0A = (f32x4){0.f,0.f,0.f,0.f}, a0B = a0A, a0C = a0A, a0D = a0A;
      f32x4 a1A = a0A, a1B = a0A, a1C = a0A, a1D = a0A;
      __builtin_amdgcn_s_setprio(1);
      a0A = __builtin_amdgcn_mfma_f32_16x16x32_bf16(afr[0], wf[0][0], a0A, 0, 0, 0);
      a1A = __builtin_amdgcn_mfma_f32_16x16x32_bf16(afr[0], wf[1][0], a1A, 0, 0, 0);
      a0B = __builtin_amdgcn_mfma_f32_16x16x32_bf16(afr[1], wf[0][1], a0B, 0, 0, 0);
      a1B = __builtin_amdgcn_mfma_f32_16x16x32_bf16(afr[1], wf[1][1], a1B, 0, 0, 0);
      a0C = __builtin_amdgcn_mfma_f32_16x16x32_bf16(afr[2], wf[0][2], a0C, 0, 0, 0);
      a1C = __builtin_amdgcn_mfma_f32_16x16x32_bf16(afr[2], wf[1][2], a1C, 0, 0, 0);
      a0D = __builtin_amdgcn_mfma_f32_16x16x32_bf16(afr[3], wf[0][3], a0D, 0, 0, 0);
      a1D = __builtin_amdgcn_mfma_f32_16x16x32_bf16(afr[3], wf[1][3], a1D, 0, 0, 0);
      a0A = __builtin_amdgcn_mfma_f32_16x16x32_bf16(afr[4], wf[0][4], a0A, 0, 0, 0);
      a1A = __builtin_amdgcn_mfma_f32_16x16x32_bf16(afr[4], wf[1][4], a1A, 0, 0, 0);
      a0B = __builtin_amdgcn_mfma_f32_16x16x32_bf16(afr[5], wf[0][5], a0B, 0, 0, 0);
      a1B = __builtin_amdgcn_mfma_f32_16x16x32_bf16(afr[5], wf[1][5], a1B, 0, 0, 0);
      a0C = __builtin_amdgcn_mfma_f32_16x16x32_bf16(afr[6], wf[0][6], a0C, 0, 0, 0);
      a1C = __builtin_amdgcn_mfma_f32_16x16x32_bf16(afr[6], wf[1][6], a1C, 0, 0, 0);
      a0D = __builtin_amdgcn_mfma_f32_16x16x32_bf16(afr[7], wf[0][7], a0D, 0, 0, 0);
      a1D = __builtin_amdgcn_mfma_f32_16x16x32_bf16(afr[7], wf[1][7], a1D, 0, 0, 0);
      __builtin_amdgcn_s_setprio(0);
      f32x4 acc0 = (a0A + a0B) + (a0C + a0D);
      f32x4 acc1 = (a1A + a1B) + (a1C + a1D);
      // per-lane select: n-tile = quad&1, batch pair = quad>>1
      f32x4 a = (quad & 1) ? acc1 : acc0;
      float s0 = (quad >> 1) ? a[2] : a[0];
      float s1 = (quad >> 1) ? a[3] : a[1];
      float xv0 = bitsf(xq[j] << 16);
      float xv1 = bitsf(xq[j] & 0xffff0000u);
      float y0 = fmaf(2.0f, s0, xv0);
      float y1 = fmaf(2.0f, s1, xv1);
      float h0 = fmaf(-2.0f, __builtin_amdgcn_rcpf(__expf(y0) + 1.0f), 1.0f);
      float h1 = fmaf(-2.0f, __builtin_amdgcn_rcpf(__expf(y1) + 1.0f), 1.0f);
      if (j < 15 || tc < SEQ/16 - 1) {
        hbuf[1 - cur][ rb      * 272 + col_e] = f2bf_fast(h0);
        hbuf[1 - cur][(rb + 1) * 272 + col_e] = f2bf_fast(h1);
      } else {
        hT[(size_t)(g*4 + rb    ) * HID + col_e] = h0;
        hT[(size_t)(g*4 + rb + 1) * HID + col_e] = h1;
      }
      barrier_lgkm();                                // no vmcnt(0) drain
    }
    if (tc < SEQ/16 - 1) {
      #pragma unroll
      for (int j = 0; j < 16; ++j)                   // rotate: loads had ~16
        xq[j] = xqn[j];                              // windows to land
    }
  }
}

// ---------------- kernel 3: logits + log_softmax. 1 wave/batch.
__global__ __launch_bounds__(64) void fc_head(const float* __restrict__ hT,
    const float* __restrict__ W_fc, const float* __restrict__ b_fc,
    float* __restrict__ out)
{
  const int b = blockIdx.x;
  const int l = threadIdx.x;
  float s0 = 0.f, s1 = 0.f;
  #pragma unroll
  for (int j0 = 0; j0 < HID; j0 += 64) {
    float h = hT[(size_t)b * HID + j0 + l];
    s0 += h * W_fc[j0 + l];
    s1 += h * W_fc[HID + j0 + l];
  }
  #pragma unroll
  for (int off = 32; off > 0; off >>= 1) {
    s0 += __shfl_xor(s0, off, 64);
    s1 += __shfl_xor(s1, off, 64);
  }
  if (l == 0) {
    float l0 = s0 + b_fc[0], l1 = s1 + b_fc[1];
    float m = fmaxf(l0, l1);
    float lse = m + logf(expf(l0 - m) + expf(l1 - m));
    out[b*2 + 0] = l0 - lse;
    out[b*2 + 1] = l1 - lse;
  }
}

extern "C" void kernel_launch(void* const* d_in, const int* in_sizes, int n_in,
                              void* d_out, int out_size, void* d_ws, size_t ws_size,
                              hipStream_t stream) {
  const float* x    = (const float*)d_in[0];
  const float* W_ih = (const float*)d_in[1];
  const float* W_hh = (const float*)d_in[2];
  const float* b_ih = (const float*)d_in[3];
  const float* b_hh = (const float*)d_in[4];
  const float* W_fc = (const float*)d_in[5];
  const float* b_fc = (const float*)d_in[6];
  float* out = (float*)d_out;

  const size_t xp_bytes = (size_t)SEQ * BATCH * HID * 2;   // 67,108,864
  const size_t wb_bytes = (size_t)256 * 320 * 2;
  const size_t ht_bytes = (size_t)BATCH * HID * 4;
  if (ws_size < xp_bytes + wb_bytes + ht_bytes) return;

  char* ws = (char*)d_ws;
  unsigned int*   xp2  = (unsigned int*)ws;
  unsigned short* w_bf = (unsigned short*)(ws + xp_bytes);
  float*          hT   = (float*)(ws + xp_bytes + wb_bytes);

  hipLaunchKernelGGL(conv_wih, dim3(320),  dim3(256), 0, stream, W_ih, w_bf);
  hipLaunchKernelGGL(gemm_xp,  dim3(1024), dim3(512), 0, stream, x, w_bf, b_ih, b_hh, xp2);
  hipLaunchKernelGGL(rnn_scan, dim3(64),   dim3(512), 0, stream, W_hh, xp2, hT);
  hipLaunchKernelGGL(fc_head,  dim3(BATCH), dim3(64), 0, stream, hT, W_fc, b_fc, out);
}

// Round 4
// 482.883 us; speedup vs baseline: 1.0426x; 1.0426x over previous
//
#include <hip/hip_runtime.h>
#include <hip/hip_bf16.h>
#include <cstdint>
#include <cstddef>

#define SEQ 512
#define BATCH 256
#define IN_DIM 300
#define HID 256

typedef __attribute__((ext_vector_type(8))) short bf16x8;
typedef __attribute__((ext_vector_type(4))) float f32x4;
typedef __attribute__((ext_vector_type(4))) unsigned int u32x4;

__device__ __forceinline__ unsigned short f2bf(float f) {
  union { float f; unsigned int u; } v; v.f = f;
  unsigned int u = v.u;
  return (unsigned short)((u + 0x7fffu + ((u >> 16) & 1u)) >> 16);  // RNE
}
__device__ __forceinline__ unsigned short f2bf_fast(float f) {
  union { float f; unsigned int u; } v; v.f = f;
  return (unsigned short)((v.u + 0x8000u) >> 16);  // round-half-up, err <= 2^-9 rel
}
__device__ __forceinline__ float bitsf(unsigned int u) {
  union { unsigned int u; float f; } v; v.u = u; return v.f;
}
// HW cvt_pk RNE pack of two f32 -> one dword (low = lo).
__device__ __forceinline__ unsigned int cvtpk(float lo, float hi) {
  union { __hip_bfloat162 h; unsigned int u; } c;
  c.h = __float22bfloat162_rn(make_float2(lo, hi));
  return c.u;
}
__device__ __forceinline__ bf16x8 cvt8(float a0,float a1,float a2,float a3,
                                       float a4,float a5,float a6,float a7) {
  union { __hip_bfloat162 h2[4]; bf16x8 v; } c;
  c.h2[0] = __float22bfloat162_rn(make_float2(a0, a1));
  c.h2[1] = __float22bfloat162_rn(make_float2(a2, a3));
  c.h2[2] = __float22bfloat162_rn(make_float2(a4, a5));
  c.h2[3] = __float22bfloat162_rn(make_float2(a6, a7));
  return c.v;
}
// Raw workgroup barrier with LDS-only drain: does NOT force vmcnt(0), so
// global-load prefetches stay in flight across the barrier (T4 pattern).
// Always executed in block-uniform control flow.
__device__ __forceinline__ void barrier_lgkm() {
  asm volatile("s_waitcnt lgkmcnt(0)" ::: "memory");
  __builtin_amdgcn_s_barrier();
  asm volatile("" ::: "memory");
}

struct F8 { float v[8]; };
// guarded 8-float row load (zero-pad past IN_DIM); fully unrolled -> registers
__device__ __forceinline__ F8 load_x8(const float* __restrict__ xrow, int k0, int ac) {
  F8 r;
  if (k0 + ac + 8 <= IN_DIM) {
    float2 p0 = *(const float2*)(xrow + k0 + ac + 0);
    float2 p1 = *(const float2*)(xrow + k0 + ac + 2);
    float2 p2 = *(const float2*)(xrow + k0 + ac + 4);
    float2 p3 = *(const float2*)(xrow + k0 + ac + 6);
    r.v[0]=p0.x; r.v[1]=p0.y; r.v[2]=p1.x; r.v[3]=p1.y;
    r.v[4]=p2.x; r.v[5]=p2.y; r.v[6]=p3.x; r.v[7]=p3.y;
  } else {
    #pragma unroll
    for (int j = 0; j < 8; ++j)
      r.v[j] = (k0 + ac + j < IN_DIM) ? xrow[k0 + ac + j] : 0.f;
  }
  return r;
}

// ---------------- kernel 0: W_ih fp32 -> bf16, FRAGMENT-MAJOR layout.
// Short index: (((n16*10 + kc)*4 + quad)*16 + l15)*8 + j
//   value = W_ih[n16*16 + l15][kc*32 + quad*8 + j]  (0 if k >= 300)
__global__ __launch_bounds__(256) void conv_wih(const float* __restrict__ w,
                                                unsigned short* __restrict__ w_bf) {
  int idx = blockIdx.x * 256 + threadIdx.x;    // 0..81919
  int j    = idx & 7;
  int l15  = (idx >> 3) & 15;
  int quad = (idx >> 7) & 3;
  int t    = idx >> 9;                         // n16*10 + kc
  int n16  = t / 10;
  int kc   = t - n16 * 10;
  int n = n16 * 16 + l15;
  int k = kc * 32 + quad * 8 + j;
  float v = (k < IN_DIM) ? w[n * IN_DIM + k] : 0.f;
  w_bf[idx] = f2bf(v);
}

// ---------------- kernel 1: xp2 (permuted, bf16) = 2*(x@W_ih^T + b_ih + b_hh)
// (byte-identical to round-3 version so this round's counters attribute to it)
__global__ __launch_bounds__(512, 2) void gemm_xp(const float* __restrict__ x,
    const unsigned short* __restrict__ w_bf, const float* __restrict__ b_ih,
    const float* __restrict__ b_hh, unsigned int* __restrict__ xp2)
{
  __shared__ unsigned int a_lds[2][128][20];   // packed bf16 pairs, row stride 80 B
  const int tid  = threadIdx.x;
  const int wave = tid >> 6;
  const int lane = tid & 63;
  const int l15  = lane & 15;
  const int quad = lane >> 4;
  const long m0  = (long)blockIdx.x * 128;

  // B fragments, fragment-major coalesced: n16 = wave*2+nt
  bf16x8 wf[2][10];
  #pragma unroll
  for (int nt = 0; nt < 2; ++nt) {
    const unsigned short* wp =
        w_bf + ((size_t)((wave*2 + nt)*10)*4 + quad)*16*8 + (size_t)l15*8;
    #pragma unroll
    for (int kc = 0; kc < 10; ++kc)
      wf[nt][kc] = *(const bf16x8*)(wp + (size_t)kc*4*16*8);
  }

  f32x4 acc[8][2];
  #pragma unroll
  for (int mt = 0; mt < 8; ++mt) {
    acc[mt][0] = (f32x4){0.f, 0.f, 0.f, 0.f};
    acc[mt][1] = (f32x4){0.f, 0.f, 0.f, 0.f};
  }

  const int ar = tid >> 2;            // A row 0..127
  const int ac = (tid & 3) * 8;       // A col base 0/8/16/24
  const float* xrow = x + (size_t)(m0 + ar) * IN_DIM;

  F8 av[2];
  av[0] = load_x8(xrow, 0, ac);       // kc=0
  av[1] = load_x8(xrow, 32, ac);      // kc=1
  {
    u32x4 pk;
    pk.x = cvtpk(av[0].v[0], av[0].v[1]);
    pk.y = cvtpk(av[0].v[2], av[0].v[3]);
    pk.z = cvtpk(av[0].v[4], av[0].v[5]);
    pk.w = cvtpk(av[0].v[6], av[0].v[7]);
    *(u32x4*)&a_lds[0][ar][(tid & 3) * 4] = pk;
  }
  barrier_lgkm();

  #pragma unroll
  for (int kc = 0; kc < 10; ++kc) {
    const int cur = kc & 1;
    bf16x8 afr[8];
    #pragma unroll
    for (int mt = 0; mt < 8; ++mt)
      afr[mt] = *(const bf16x8*)&a_lds[cur][mt*16 + l15][quad*4];
    if (kc < 9) {
      const int s = (kc + 1) & 1;
      u32x4 pk;
      pk.x = cvtpk(av[s].v[0], av[s].v[1]);
      pk.y = cvtpk(av[s].v[2], av[s].v[3]);
      pk.z = cvtpk(av[s].v[4], av[s].v[5]);
      pk.w = cvtpk(av[s].v[6], av[s].v[7]);
      *(u32x4*)&a_lds[s][ar][(tid & 3) * 4] = pk;
    }
    if (kc < 8)
      av[kc & 1] = load_x8(xrow, (kc + 2) * 32, ac);
    #pragma unroll
    for (int mt = 0; mt < 8; ++mt) {
      acc[mt][0] = __builtin_amdgcn_mfma_f32_16x16x32_bf16(afr[mt], wf[0][kc], acc[mt][0], 0, 0, 0);
      acc[mt][1] = __builtin_amdgcn_mfma_f32_16x16x32_bf16(afr[mt], wf[1][kc], acc[mt][1], 0, 0, 0);
    }
    barrier_lgkm();
  }

  // epilogue: scatter to scan-permuted layout (bit-identical formula/rounding)
  const int t  = (int)(blockIdx.x >> 1);
  const int b4 = ((int)blockIdx.x & 1) * 32;
  #pragma unroll
  for (int nt = 0; nt < 2; ++nt) {
    const int n = wave*32 + nt*16 + l15;
    const float kb = 2.0f * (b_ih[n] + b_hh[n]);
    const int tid_lo = wave*64 + nt*16 + l15;
    #pragma unroll
    for (int mt = 0; mt < 8; ++mt) {
      const int g = b4 + mt*4 + quad;
      const size_t base = ((size_t)t*64 + g) * 512;
      float y0 = fmaf(2.0f, acc[mt][nt][0], kb);
      float y1 = fmaf(2.0f, acc[mt][nt][1], kb);
      float y2 = fmaf(2.0f, acc[mt][nt][2], kb);
      float y3 = fmaf(2.0f, acc[mt][nt][3], kb);
      xp2[base + tid_lo]      = cvtpk(y0, y1);
      xp2[base + tid_lo + 32] = cvtpk(y2, y3);
    }
  }
}

// ---------------- kernel 2: sequential scan. EXACT revert to round-2 code
// (best measured: 224 us). Round-3's quad-acc + setprio + launch_bounds(,2)
// regressed to 249: the acc-combine VALU adds sat on the serial path and
// setprio is null-to-negative in barrier-lockstep loops (m190).
__global__ __launch_bounds__(512) void rnn_scan(const float* __restrict__ W_hh,
    const unsigned int* __restrict__ xp2, float* __restrict__ hT)
{
  __shared__ alignas(16) unsigned short hbuf[2][4 * 272];
  const int tid  = threadIdx.x;
  const int wave = tid >> 6;
  const int lane = tid & 63;
  const int l15  = lane & 15;
  const int quad = lane >> 4;
  const int g = blockIdx.x;
  const int c0 = wave * 32;

  // B fragments: B[k=quad*8+j][n=l15] = W_hh[n][k]
  bf16x8 wf[2][8];
  #pragma unroll
  for (int nt = 0; nt < 2; ++nt) {
    const int n = c0 + nt*16 + l15;
    #pragma unroll
    for (int kc = 0; kc < 8; ++kc) {
      const float* src = W_hh + n*HID + kc*32 + quad*8;
      float4 p0 = *(const float4*)src;
      float4 p1 = *(const float4*)(src + 4);
      wf[nt][kc] = cvt8(p0.x,p0.y,p0.z,p0.w,p1.x,p1.y,p1.z,p1.w);
    }
  }

  const int rb    = (quad >> 1) * 2;                 // batch pair base: rb, rb+1
  const int col_e = c0 + (quad & 1) * 16 + l15;      // epilogue hidden col
  const int abase = (l15 & 3) * 272 + quad * 8;      // A-frag read base

  for (int i = tid; i < 4 * 272; i += 512) hbuf[0][i] = 0;  // h0 = 0

  const unsigned int* xbase = xp2 + (size_t)g * 512 + tid;  // t stride 64*512 dwords

  __syncthreads();

  unsigned int xq[16], xqn[16];
  #pragma unroll
  for (int j = 0; j < 16; ++j)                       // preload tc=0
    xq[j] = xbase[(size_t)j * 32768];

  for (int tc = 0; tc < SEQ / 16; ++tc) {
    if (tc < SEQ/16 - 1) {                           // issue tc+1 burst early
      const unsigned int* pn = xbase + (size_t)(tc + 1) * 16 * 32768;
      #pragma unroll
      for (int j = 0; j < 16; ++j)
        xqn[j] = pn[(size_t)j * 32768];
    }
    #pragma unroll
    for (int j = 0; j < 16; ++j) {
      const int cur = j & 1;                         // t parity == j parity
      bf16x8 afr[8];
      #pragma unroll
      for (int kc = 0; kc < 8; ++kc)
        afr[kc] = *(const bf16x8*)&hbuf[cur][abase + kc*32];
      f32x4 a0A = (f32x4){0.f,0.f,0.f,0.f}, a0B = a0A, a1A = a0A, a1B = a0A;
      #pragma unroll
      for (int kc = 0; kc < 8; kc += 2) {
        a0A = __builtin_amdgcn_mfma_f32_16x16x32_bf16(afr[kc],   wf[0][kc],   a0A, 0, 0, 0);
        a1A = __builtin_amdgcn_mfma_f32_16x16x32_bf16(afr[kc],   wf[1][kc],   a1A, 0, 0, 0);
        a0B = __builtin_amdgcn_mfma_f32_16x16x32_bf16(afr[kc+1], wf[0][kc+1], a0B, 0, 0, 0);
        a1B = __builtin_amdgcn_mfma_f32_16x16x32_bf16(afr[kc+1], wf[1][kc+1], a1B, 0, 0, 0);
      }
      f32x4 acc0 = a0A + a0B;
      f32x4 acc1 = a1A + a1B;
      // per-lane select: n-tile = quad&1, batch pair = quad>>1
      f32x4 a = (quad & 1) ? acc1 : acc0;
      float s0 = (quad >> 1) ? a[2] : a[0];
      float s1 = (quad >> 1) ? a[3] : a[1];
      float xv0 = bitsf(xq[j] << 16);
      float xv1 = bitsf(xq[j] & 0xffff0000u);
      float y0 = fmaf(2.0f, s0, xv0);
      float y1 = fmaf(2.0f, s1, xv1);
      float h0 = fmaf(-2.0f, __builtin_amdgcn_rcpf(__expf(y0) + 1.0f), 1.0f);
      float h1 = fmaf(-2.0f, __builtin_amdgcn_rcpf(__expf(y1) + 1.0f), 1.0f);
      if (j < 15 || tc < SEQ/16 - 1) {
        hbuf[1 - cur][ rb      * 272 + col_e] = f2bf_fast(h0);
        hbuf[1 - cur][(rb + 1) * 272 + col_e] = f2bf_fast(h1);
      } else {
        hT[(size_t)(g*4 + rb    ) * HID + col_e] = h0;
        hT[(size_t)(g*4 + rb + 1) * HID + col_e] = h1;
      }
      barrier_lgkm();                                // no vmcnt(0) drain
    }
    if (tc < SEQ/16 - 1) {
      #pragma unroll
      for (int j = 0; j < 16; ++j)                   // rotate: loads had ~16
        xq[j] = xqn[j];                              // windows to land
    }
  }
}

// ---------------- kernel 3: logits + log_softmax. 1 wave/batch.
__global__ __launch_bounds__(64) void fc_head(const float* __restrict__ hT,
    const float* __restrict__ W_fc, const float* __restrict__ b_fc,
    float* __restrict__ out)
{
  const int b = blockIdx.x;
  const int l = threadIdx.x;
  float s0 = 0.f, s1 = 0.f;
  #pragma unroll
  for (int j0 = 0; j0 < HID; j0 += 64) {
    float h = hT[(size_t)b * HID + j0 + l];
    s0 += h * W_fc[j0 + l];
    s1 += h * W_fc[HID + j0 + l];
  }
  #pragma unroll
  for (int off = 32; off > 0; off >>= 1) {
    s0 += __shfl_xor(s0, off, 64);
    s1 += __shfl_xor(s1, off, 64);
  }
  if (l == 0) {
    float l0 = s0 + b_fc[0], l1 = s1 + b_fc[1];
    float m = fmaxf(l0, l1);
    float lse = m + logf(expf(l0 - m) + expf(l1 - m));
    out[b*2 + 0] = l0 - lse;
    out[b*2 + 1] = l1 - lse;
  }
}

extern "C" void kernel_launch(void* const* d_in, const int* in_sizes, int n_in,
                              void* d_out, int out_size, void* d_ws, size_t ws_size,
                              hipStream_t stream) {
  const float* x    = (const float*)d_in[0];
  const float* W_ih = (const float*)d_in[1];
  const float* W_hh = (const float*)d_in[2];
  const float* b_ih = (const float*)d_in[3];
  const float* b_hh = (const float*)d_in[4];
  const float* W_fc = (const float*)d_in[5];
  const float* b_fc = (const float*)d_in[6];
  float* out = (float*)d_out;

  const size_t xp_bytes = (size_t)SEQ * BATCH * HID * 2;   // 67,108,864
  const size_t wb_bytes = (size_t)256 * 320 * 2;
  const size_t ht_bytes = (size_t)BATCH * HID * 4;
  if (ws_size < xp_bytes + wb_bytes + ht_bytes) return;

  char* ws = (char*)d_ws;
  unsigned int*   xp2  = (unsigned int*)ws;
  unsigned short* w_bf = (unsigned short*)(ws + xp_bytes);
  float*          hT   = (float*)(ws + xp_bytes + wb_bytes);

  hipLaunchKernelGGL(conv_wih, dim3(320),  dim3(256), 0, stream, W_ih, w_bf);
  hipLaunchKernelGGL(gemm_xp,  dim3(1024), dim3(512), 0, stream, x, w_bf, b_ih, b_hh, xp2);
  hipLaunchKernelGGL(rnn_scan, dim3(64),   dim3(512), 0, stream, W_hh, xp2, hT);
  hipLaunchKernelGGL(fc_head,  dim3(BATCH), dim3(64), 0, stream, hT, W_fc, b_fc, out);
}